// Round 1
// baseline (1225.225 us; speedup 1.0000x reference)
//
#include <hip/hip_runtime.h>
#include <math.h>

#define BATCH 128
#define NR 2312          // 8*17*17 routes
#define RC 68            // route chunk
#define NCH 34           // NR / RC
#define NC 10            // caps
#define OC 16            // out ch
#define IC 8             // in ch

// ---- workspace layout (float offsets) ----
#define OFF_X1    0                        // 128*32*41*41 = 6885376
#define OFF_U0    6885376                  // 128*64*289   = 2367488
#define OFF_XT    9252864                  // 2312*8*128   = 2367488
#define OFF_SC    11620352                 // 1024
#define OFF_BIJ   11621376                 // 23120
#define OFF_C     11644496                 // 23120
#define OFF_SP    11667616                 // 34*10*16*128 = 696320
#define OFF_V     12363936                 // 20480

__global__ void k_zero(float* __restrict__ p, int n) {
    int i = blockIdx.x * 256 + threadIdx.x;
    if (i < n) p[i] = 0.f;
}

// conv1 + bias + relu: data(128,3,49,49) -> x1(128,32,41,41)
__global__ __launch_bounds__(512) void k_conv1(const float* __restrict__ data,
                                               const float* __restrict__ cw,
                                               const float* __restrict__ cb,
                                               float* __restrict__ x1) {
    int b = blockIdx.x >> 2, cog = blockIdx.x & 3;   // 8 out-ch per block
    __shared__ float in_s[3 * 49 * 52];              // row stride 52 (cols 49..51 garbage, never stored)
    __shared__ float w_s[8 * 243];
    __shared__ float b_s[8];
    for (int k = threadIdx.x; k < 3 * 49 * 49; k += 512) {
        int ci = k / 2401, rem = k % 2401;
        int r = rem / 49, cc = rem % 49;
        in_s[ci * 2548 + r * 52 + cc] = data[(b * 3 + ci) * 2401 + rem];
    }
    for (int k = threadIdx.x; k < 8 * 243; k += 512)
        w_s[k] = cw[cog * 8 * 243 + k];
    if (threadIdx.x < 8) b_s[threadIdx.x] = cb[cog * 8 + threadIdx.x];
    __syncthreads();
    int t = threadIdx.x;
    if (t >= 451) return;                 // 41 h * 11 w-groups
    int h = t / 11, w0 = (t % 11) * 4;
    float acc[8][4];
#pragma unroll
    for (int co = 0; co < 8; co++)
#pragma unroll
        for (int j = 0; j < 4; j++) acc[co][j] = 0.f;
    for (int ci = 0; ci < 3; ci++) {
#pragma unroll
        for (int kh = 0; kh < 9; kh++) {
            const float* row = &in_s[ci * 2548 + (h + kh) * 52 + w0];
            float in[12];
#pragma unroll
            for (int j = 0; j < 12; j++) in[j] = row[j];
#pragma unroll
            for (int co = 0; co < 8; co++) {
                const float* wr = &w_s[co * 243 + ci * 81 + kh * 9];
#pragma unroll
                for (int kw = 0; kw < 9; kw++) {
                    float wt = wr[kw];
#pragma unroll
                    for (int j = 0; j < 4; j++) acc[co][j] = fmaf(wt, in[kw + j], acc[co][j]);
                }
            }
        }
    }
#pragma unroll
    for (int co = 0; co < 8; co++) {
        float bias = b_s[co];
#pragma unroll
        for (int j = 0; j < 4; j++) {
            int w = w0 + j;
            if (w < 41) {
                float val = acc[co][j] + bias;
                x1[((b * 32 + cog * 8 + co) * 41 + h) * 41 + w] = val > 0.f ? val : 0.f;
            }
        }
    }
}

// conv2 (stride2) + bias: x1(128,32,41,41) -> u0(128,64,17,17)
__global__ __launch_bounds__(256) void k_conv2(const float* __restrict__ x1,
                                               const float* __restrict__ pw,
                                               const float* __restrict__ pb,
                                               float* __restrict__ u0) {
    int btri = blockIdx.x >> 4, cog = blockIdx.x & 15;   // 4 out-ch per block, 3 batches per block
    __shared__ float w_s[4 * 32 * 81];                   // 41.5 KB
    for (int k = threadIdx.x; k < 4 * 32 * 81; k += 256)
        w_s[k] = pw[cog * 4 * 32 * 81 + k];
    __syncthreads();
    int t = threadIdx.x;
    int which = t / 85;
    int b = btri * 3 + which;
    if (which >= 3 || b >= BATCH) return;
    int rem = t % 85;
    int h = rem / 5, w0 = (rem % 5) * 4;
    float acc[4][4];
#pragma unroll
    for (int co = 0; co < 4; co++)
#pragma unroll
        for (int j = 0; j < 4; j++) acc[co][j] = 0.f;
    for (int ci = 0; ci < 32; ci++) {
#pragma unroll
        for (int kh = 0; kh < 9; kh++) {
            const float* xrow = &x1[((b * 32 + ci) * 41 + (2 * h + kh)) * 41 + 2 * w0];
            float in[15];
#pragma unroll
            for (int j = 0; j < 15; j++) in[j] = xrow[j];   // tail lanes read a few floats past row; never stored
#pragma unroll
            for (int co = 0; co < 4; co++) {
                const float* wr = &w_s[(co * 32 + ci) * 81 + kh * 9];
#pragma unroll
                for (int kw = 0; kw < 9; kw++) {
                    float wt = wr[kw];
#pragma unroll
                    for (int j = 0; j < 4; j++) acc[co][j] = fmaf(wt, in[kw + 2 * j], acc[co][j]);
                }
            }
        }
    }
#pragma unroll
    for (int co = 0; co < 4; co++) {
        float bias = pb[cog * 4 + co];
#pragma unroll
        for (int j = 0; j < 4; j++) {
            int w = w0 + j;
            if (w < 17)
                u0[((b * 64 + cog * 4 + co) * 17 + h) * 17 + w] = acc[co][j] + bias;
        }
    }
}

// per-(b,i) squash scale over 2312 routes (contiguous: channels i*8..i*8+7)
__global__ void k_sumsq(const float* __restrict__ u0, float* __restrict__ scale) {
    int bi = blockIdx.x;                     // b*8 + i
    const float* base = &u0[bi * 8 * 289];
    float sum = 0.f;
    for (int k = threadIdx.x; k < 2312; k += 256) { float v = base[k]; sum += v * v; }
#pragma unroll
    for (int d = 32; d; d >>= 1) sum += __shfl_xor(sum, d);
    __shared__ float red[4];
    if ((threadIdx.x & 63) == 0) red[threadIdx.x >> 6] = sum;
    __syncthreads();
    if (threadIdx.x == 0) {
        float sn = red[0] + red[1] + red[2] + red[3];
        scale[bi] = sn / ((1.f + sn) * sqrtf(sn));
    }
}

// build xT[r][i][b] = u0[b][i*8+j][hw] * scale[b,i]   (r = j*289+hw)
__global__ void k_xt(const float* __restrict__ u0, const float* __restrict__ scale,
                     float* __restrict__ xT) {
    int idx = blockIdx.x * 256 + threadIdx.x;   // (r,i)
    if (idx >= NR * 8) return;
    int r = idx >> 3, i = idx & 7;
    int j = r / 289, hw = r % 289;
    const float* src = &u0[(i * 8 + j) * 289 + hw];
    float* dst = &xT[(size_t)idx * 128];
    for (int b = 0; b < 128; b += 4) {
        float4 o4;
        o4.x = src[(b + 0) * 18496] * scale[(b + 0) * 8 + i];
        o4.y = src[(b + 1) * 18496] * scale[(b + 1) * 8 + i];
        o4.z = src[(b + 2) * 18496] * scale[(b + 2) * 8 + i];
        o4.w = src[(b + 3) * 18496] * scale[(b + 3) * 8 + i];
        *(float4*)&dst[b] = o4;
    }
}

// softmax over caps per route
__global__ void k_softmax(const float* __restrict__ bij, float* __restrict__ cmat) {
    int r = blockIdx.x * 256 + threadIdx.x;
    if (r >= NR) return;
    float x[NC];
    float m = -1e30f;
#pragma unroll
    for (int k = 0; k < NC; k++) { x[k] = bij[r * NC + k]; m = fmaxf(m, x[k]); }
    float s = 0.f;
#pragma unroll
    for (int k = 0; k < NC; k++) { x[k] = expf(x[k] - m); s += x[k]; }
    float inv = 1.f / s;
#pragma unroll
    for (int k = 0; k < NC; k++) cmat[r * NC + k] = x[k] * inv;
}

// s partials: block (chunk,c) computes spart[chunk][c][o][b] = sum over 68 routes
__global__ __launch_bounds__(256) void k_s(const float* __restrict__ xT,
                                           const float* __restrict__ W,
                                           const float* __restrict__ cmat,
                                           float* __restrict__ spart) {
    int chunk = blockIdx.x / NC, c = blockIdx.x % NC;
    int r0 = chunk * RC;
    __shared__ float Wc[RC * 128];
    __shared__ float cs[RC];
    for (int k = threadIdx.x; k < RC * 128; k += 256) {
        int rr = k >> 7, kk = k & 127;
        Wc[k] = W[(size_t)(r0 + rr) * 1280 + c * 128 + kk];
    }
    if (threadIdx.x < RC) cs[threadIdx.x] = cmat[(r0 + threadIdx.x) * NC + c];
    __syncthreads();
    int bl = threadIdx.x & 63;
    int oq = threadIdx.x >> 6;       // wave-uniform
    float acc0[4] = {0.f, 0.f, 0.f, 0.f};
    float acc1[4] = {0.f, 0.f, 0.f, 0.f};
    for (int rr = 0; rr < RC; rr++) {
        const float* xrow = &xT[(size_t)(r0 + rr) * 8 * 128];
        float xa[8], xb[8];
#pragma unroll
        for (int i = 0; i < 8; i++) { xa[i] = xrow[i * 128 + bl]; xb[i] = xrow[i * 128 + bl + 64]; }
        float cr = cs[rr];
        const float* wrow = &Wc[rr * 128 + oq * 32];
#pragma unroll
        for (int oo = 0; oo < 4; oo++) {
            float4 wA = *(const float4*)&wrow[oo * 8];
            float4 wB = *(const float4*)&wrow[oo * 8 + 4];
            float d0 = wA.x * xa[0] + wA.y * xa[1] + wA.z * xa[2] + wA.w * xa[3]
                     + wB.x * xa[4] + wB.y * xa[5] + wB.z * xa[6] + wB.w * xa[7];
            float d1 = wA.x * xb[0] + wA.y * xb[1] + wA.z * xb[2] + wA.w * xb[3]
                     + wB.x * xb[4] + wB.y * xb[5] + wB.z * xb[6] + wB.w * xb[7];
            acc0[oo] = fmaf(cr, d0, acc0[oo]);
            acc1[oo] = fmaf(cr, d1, acc1[oo]);
        }
    }
    float* sp = &spart[((size_t)(chunk * NC + c) * 16) * 128];
#pragma unroll
    for (int oo = 0; oo < 4; oo++) {
        int o = oq * 4 + oo;
        sp[o * 128 + bl] = acc0[oo];
        sp[o * 128 + bl + 64] = acc1[oo];
    }
}

// reduce spart over chunks, squash over o -> v (and d_out[0:20480])
__global__ void k_v(const float* __restrict__ spart, float* __restrict__ v,
                    float* __restrict__ out) {
    int idx = blockIdx.x * 256 + threadIdx.x;     // (bc, o), o = low 4 bits
    int o = idx & 15;
    int bc = idx >> 4;
    int c = bc % NC, b = bc / NC;
    float s = 0.f;
    for (int k = 0; k < NCH; k++)
        s += spart[((size_t)(k * NC + c) * 16 + o) * 128 + b];
    float sq = s * s;
#pragma unroll
    for (int d = 1; d < 16; d <<= 1) sq += __shfl_xor(sq, d);
    float sn = sq;
    float vv = s * sn / ((1.f + sn) * sqrtf(sn));
    v[idx] = vv;
    out[idx] = vv;
}

// a[r,c] = 1/B * sum_{i,o} W[r,c,o,i] * (sum_b xT[r,i,b] * v[b,c,o]);  bij += a
__global__ __launch_bounds__(256) void k_a(const float* __restrict__ xT,
                                           const float* __restrict__ W,
                                           const float* __restrict__ v,
                                           float* __restrict__ bij) {
    int chunk = blockIdx.x / NC, c = blockIdx.x % NC;
    int r0 = chunk * RC;
    __shared__ float Vs[16 * 132];        // stride 132: bank-spread + 16B aligned
    __shared__ float red[4];
    for (int k = threadIdx.x; k < 2048; k += 256) {
        int o = k & 15, b = k >> 4;
        Vs[o * 132 + b] = v[(b * NC + c) * 16 + o];
    }
    __syncthreads();
    int t = threadIdx.x;
    int half = t >> 7;
    int i = t & 7;
    int o = (t >> 3) & 15;
    const float* vr = &Vs[o * 132];
    for (int rs = 0; rs < NCH; rs++) {
        int r = r0 + rs * 2 + half;
        const float* xr = &xT[(size_t)(r * 8 + i) * 128];
        float g = 0.f;
#pragma unroll 8
        for (int bb = 0; bb < 128; bb += 4) {
            float4 xv = *(const float4*)&xr[bb];
            float4 vv = *(const float4*)&vr[bb];
            g = fmaf(xv.x, vv.x, g); g = fmaf(xv.y, vv.y, g);
            g = fmaf(xv.z, vv.z, g); g = fmaf(xv.w, vv.w, g);
        }
        float p = W[(size_t)r * 1280 + c * 128 + o * 8 + i] * g;
#pragma unroll
        for (int d = 1; d < 64; d <<= 1) p += __shfl_xor(p, d);
        if ((t & 63) == 0) red[t >> 6] = p;
        __syncthreads();
        if (t == 0)   bij[(r0 + rs * 2) * NC + c]     += (red[0] + red[1]) * 0.0078125f;
        if (t == 128) bij[(r0 + rs * 2 + 1) * NC + c] += (red[2] + red[3]) * 0.0078125f;
        __syncthreads();
    }
}

// head: h = tanh(v @ w1 + b1); logit = h @ w2 + b2; sigmoid
__global__ void k_head(const float* __restrict__ v, const float* __restrict__ w1,
                       const float* __restrict__ b1, const float* __restrict__ w2,
                       const float* __restrict__ b2, float* __restrict__ out) {
    int b = blockIdx.x / NC, c = blockIdx.x % NC;
    int t = threadIdx.x;
    float p = 0.f;
    if (t < 100) {
        float hs = b1[c * 100 + t];
        const float* vb = &v[(b * NC + c) * 16];
#pragma unroll
        for (int i = 0; i < 16; i++) hs = fmaf(vb[i], w1[(c * 16 + i) * 100 + t], hs);
        p = tanhf(hs) * w2[c * 100 + t];
    }
#pragma unroll
    for (int d = 1; d < 64; d <<= 1) p += __shfl_xor(p, d);
    __shared__ float red[2];
    if ((t & 63) == 0) red[t >> 6] = p;
    __syncthreads();
    if (t == 0) {
        float logit = red[0] + red[1] + b2[c];
        out[20480 + c * 128 + b] = 1.f / (1.f + expf(-logit));
    }
}

extern "C" void kernel_launch(void* const* d_in, const int* in_sizes, int n_in,
                              void* d_out, int out_size, void* d_ws, size_t ws_size,
                              hipStream_t stream) {
    const float* data   = (const float*)d_in[0];
    const float* conv_w = (const float*)d_in[1];
    const float* conv_b = (const float*)d_in[2];
    const float* prim_w = (const float*)d_in[3];
    const float* prim_b = (const float*)d_in[4];
    const float* Wd     = (const float*)d_in[5];
    const float* hw1    = (const float*)d_in[6];
    const float* hb1    = (const float*)d_in[7];
    const float* hw2    = (const float*)d_in[8];
    const float* hb2    = (const float*)d_in[9];
    float* ws = (float*)d_ws;
    float* x1    = ws + OFF_X1;
    float* u0    = ws + OFF_U0;
    float* xT    = ws + OFF_XT;
    float* scale = ws + OFF_SC;
    float* bij   = ws + OFF_BIJ;
    float* cmat  = ws + OFF_C;
    float* spart = ws + OFF_SP;
    float* v     = ws + OFF_V;
    float* out = (float*)d_out;

    k_zero<<<(23120 + 255) / 256, 256, 0, stream>>>(bij, 23120);
    k_conv1<<<128 * 4, 512, 0, stream>>>(data, conv_w, conv_b, x1);
    k_conv2<<<43 * 16, 256, 0, stream>>>(x1, prim_w, prim_b, u0);
    k_sumsq<<<1024, 256, 0, stream>>>(u0, scale);
    k_xt<<<(NR * 8 + 255) / 256, 256, 0, stream>>>(u0, scale, xT);
    for (int it = 0; it < 3; it++) {
        k_softmax<<<(NR + 255) / 256, 256, 0, stream>>>(bij, cmat);
        k_s<<<NCH * NC, 256, 0, stream>>>(xT, Wd, cmat, spart);
        k_v<<<80, 256, 0, stream>>>(spart, v, out);
        if (it < 2) k_a<<<NCH * NC, 256, 0, stream>>>(xT, Wd, v, bij);
    }
    k_head<<<128 * NC, 128, 0, stream>>>(v, hw1, hb1, hw2, hb2, out);
}